// Round 18
// baseline (608.604 us; speedup 1.0000x reference)
//
#include <hip/hip_runtime.h>

#define D 64
#define F 128
#define LDSCAP 9216  // staged words per bucket (36KB; total ~50.5KB -> 3 blocks/CU)
#define CH2 8192     // edges per part1s block

__device__ __forceinline__ unsigned short f2bf(float f) {
  unsigned int u = __float_as_uint(f);
  unsigned int r = (u + 0x7FFFu + ((u >> 16) & 1u)) >> 16;
  return (unsigned short)r;
}
__device__ __forceinline__ float bf2f(unsigned short h) {
  return __uint_as_float(((unsigned int)h) << 16);
}

#define FMA4(A_, S_, B_) \
  A_.x += (S_) * (B_).x; \
  A_.y += (S_) * (B_).y; \
  A_.z += (S_) * (B_).z; \
  A_.w += (S_) * (B_).w;

// ---- partition pass 1: staged bucket sort, int4 ILP ----------------------
__global__ __launch_bounds__(256) void k_part1s(
    const int* __restrict__ src, const int* __restrict__ dst,
    int* __restrict__ cbh, int* __restrict__ ofsmat,
    unsigned int* __restrict__ words, int E) {
  __shared__ int lhist[1024];
  __shared__ int lofs[1024];
  __shared__ int lrun[1024];
  __shared__ int sc[256];
  __shared__ unsigned int lbuf[CH2];
  const int tid = threadIdx.x;
  const int e0 = blockIdx.x * CH2;
  const int e1 = min(E, e0 + CH2);
  const int csize = e1 - e0;
  const int c4 = csize & ~3;
  for (int i = tid; i < 1024; i += 256) {
    lhist[i] = 0;
    lrun[i] = 0;
  }
  __syncthreads();
  for (int i = e0 + tid * 4; i < e0 + c4; i += 1024) {
    int4 s4 = *(const int4*)&src[i];
    atomicAdd(&lhist[s4.x >> 8], 1);
    atomicAdd(&lhist[s4.y >> 8], 1);
    atomicAdd(&lhist[s4.z >> 8], 1);
    atomicAdd(&lhist[s4.w >> 8], 1);
  }
  for (int i = e0 + c4 + tid; i < e1; i += 256) atomicAdd(&lhist[src[i] >> 8], 1);
  __syncthreads();
  const int b4 = tid * 4;
  int a0 = lhist[b4], a1 = lhist[b4 + 1], a2 = lhist[b4 + 2], a3 = lhist[b4 + 3];
  int ts = a0 + a1 + a2 + a3;
  sc[tid] = ts;
  __syncthreads();
  for (int off = 1; off < 256; off <<= 1) {
    int t = (tid >= off) ? sc[tid - off] : 0;
    __syncthreads();
    sc[tid] += t;
    __syncthreads();
  }
  int ex = sc[tid] - ts;
  lofs[b4] = ex;
  lofs[b4 + 1] = ex + a0;
  lofs[b4 + 2] = ex + a0 + a1;
  lofs[b4 + 3] = ex + a0 + a1 + a2;
  __syncthreads();
  for (int j = tid; j < 1024; j += 256) {
    ofsmat[(size_t)blockIdx.x * 1024 + j] = lofs[j];
    int c = lhist[j];
    if (c) atomicAdd(&cbh[j], c);
  }
  for (int i = e0 + tid * 4; i < e0 + c4; i += 1024) {
    int4 s4 = *(const int4*)&src[i];
    int4 d4 = *(const int4*)&dst[i];
    int b, pos;
    b = s4.x >> 8;
    pos = atomicAdd(&lrun[b], 1);
    lbuf[lofs[b] + pos] = ((unsigned int)(s4.x & 255) << 24) | (unsigned int)d4.x;
    b = s4.y >> 8;
    pos = atomicAdd(&lrun[b], 1);
    lbuf[lofs[b] + pos] = ((unsigned int)(s4.y & 255) << 24) | (unsigned int)d4.y;
    b = s4.z >> 8;
    pos = atomicAdd(&lrun[b], 1);
    lbuf[lofs[b] + pos] = ((unsigned int)(s4.z & 255) << 24) | (unsigned int)d4.z;
    b = s4.w >> 8;
    pos = atomicAdd(&lrun[b], 1);
    lbuf[lofs[b] + pos] = ((unsigned int)(s4.w & 255) << 24) | (unsigned int)d4.w;
  }
  for (int i = e0 + c4 + tid; i < e1; i += 256) {
    int s = src[i];
    int b = s >> 8;
    int pos = atomicAdd(&lrun[b], 1);
    lbuf[lofs[b] + pos] = ((unsigned int)(s & 255) << 24) | (unsigned int)dst[i];
  }
  __syncthreads();
  for (int j = tid; j < (c4 >> 2); j += 256)
    ((uint4*)&words[e0])[j] = ((const uint4*)lbuf)[j];
  for (int j = c4 + tid; j < csize; j += 256) words[e0 + j] = lbuf[j];
}

// ---- coarse scan (+ zero the small buffer) ----------
__global__ __launch_bounds__(1024) void k_cscan(const int* __restrict__ cbh,
                                                int* __restrict__ cbase,
                                                int* __restrict__ rowptr,
                                                float* __restrict__ small_,
                                                int N, int E) {
  __shared__ int s[1024];
  int tid = threadIdx.x;
  if (tid < 256) small_[tid] = 0.0f;
  int v = cbh[tid];
  s[tid] = v;
  __syncthreads();
  for (int off = 1; off < 1024; off <<= 1) {
    int t = (tid >= off) ? s[tid - off] : 0;
    __syncthreads();
    s[tid] += t;
    __syncthreads();
  }
  cbase[tid] = s[tid] - v;
  if (tid == 0) rowptr[N] = E;
}

// ---- ofsmat transpose: [NB][1024] -> [1024][NB] --------------------------
__global__ __launch_bounds__(256) void k_transp(const int* __restrict__ ofsmat,
                                                int* __restrict__ ofsmatT,
                                                int NB) {
  __shared__ int t[32][33];
  const int tx = threadIdx.x & 31, ty = threadIdx.x >> 5;
  const int bi = blockIdx.x * 32;
  const int bj = blockIdx.y * 32;
#pragma unroll
  for (int r = 0; r < 32; r += 8) {
    int i = bi + ty + r;
    t[ty + r][tx] = (i < NB) ? ofsmat[(size_t)i * 1024 + bj + tx] : 0;
  }
  __syncthreads();
#pragma unroll
  for (int r = 0; r < 32; r += 8) {
    int j = bj + ty + r;
    int i = bi + tx;
    if (i < NB) ofsmatT[(size_t)j * NB + i] = t[tx][ty + r];
  }
}

// ---- partition pass 2: serial run-walk, 3 blocks/CU ----------------------
__global__ __launch_bounds__(256) void k_part2g(
    const unsigned int* __restrict__ words, const int* __restrict__ ofsmatT,
    const int* __restrict__ cbase, int* __restrict__ rowptr,
    float* __restrict__ invdeg, int* __restrict__ adj, int NB, int N, int E) {
  __shared__ int lcntB[1024];
  __shared__ int lstB[1024];
  __shared__ int lplace[1024];
  __shared__ int sc[256];
  __shared__ int rcnt[256];
  __shared__ int rofs[256];
  __shared__ int rrun[256];
  __shared__ unsigned int lwords[LDSCAP];
  const int tid = threadIdx.x;
  const int b = blockIdx.x;
  const int p0 = cbase[b];
  const int total = cbase[b + 1] - p0;
  for (int i = tid; i < 1024; i += 256) {
    lcntB[i] = 0;
    lstB[i] = 0;
  }
  __syncthreads();
  for (int i = tid; i < NB; i += 256) {
    int st = ofsmatT[(size_t)b * NB + i];
    int chunk = min(E - i * CH2, CH2);
    int en = (b == 1023) ? chunk : ofsmatT[(size_t)(b + 1) * NB + i];
    lcntB[i] = en - st;
    lstB[i] = i * CH2 + st;
  }
  __syncthreads();
  const int b4 = tid * 4;
  int a0 = lcntB[b4], a1 = lcntB[b4 + 1], a2 = lcntB[b4 + 2], a3 = lcntB[b4 + 3];
  int ts = a0 + a1 + a2 + a3;
  sc[tid] = ts;
  __syncthreads();
  for (int off = 1; off < 256; off <<= 1) {
    int t = (tid >= off) ? sc[tid - off] : 0;
    __syncthreads();
    sc[tid] += t;
    __syncthreads();
  }
  int ex = sc[tid] - ts;
  lplace[b4] = ex;
  lplace[b4 + 1] = ex + a0;
  lplace[b4 + 2] = ex + a0 + a1;
  lplace[b4 + 3] = ex + a0 + a1 + a2;
  __syncthreads();
  rcnt[tid] = 0;
  rrun[tid] = 0;
  const bool staged = (total <= LDSCAP);
  if (staged) {
    for (int i = tid; i < NB; i += 256) {
      int c = lcntB[i], g = lstB[i], d = lplace[i];
      for (int j = 0; j < c; ++j) lwords[d + j] = words[g + j];
    }
    __syncthreads();
    for (int j = tid; j < total; j += 256) atomicAdd(&rcnt[lwords[j] >> 24], 1);
  } else {
    __syncthreads();
    for (int i = tid; i < NB; i += 256) {
      int c = lcntB[i], g = lstB[i];
      for (int j = 0; j < c; ++j) atomicAdd(&rcnt[words[g + j] >> 24], 1);
    }
  }
  __syncthreads();
  int v = rcnt[tid];
  sc[tid] = v;
  __syncthreads();
  for (int off = 1; off < 256; off <<= 1) {
    int t = (tid >= off) ? sc[tid - off] : 0;
    __syncthreads();
    sc[tid] += t;
    __syncthreads();
  }
  int exr = sc[tid] - v;
  int row = b * 256 + tid;
  if (row < N) {
    rowptr[row] = p0 + exr;
    invdeg[row] = 1.0f / fmaxf((float)v, 1.0f);
  }
  rofs[tid] = exr;
  __syncthreads();
  if (staged) {
    for (int j = tid; j < total; j += 256) {
      unsigned int w = lwords[j];
      int r = w >> 24;
      int pos = atomicAdd(&rrun[r], 1);
      adj[p0 + rofs[r] + pos] = (int)(w & 0xFFFFFFu);
    }
  } else {
    for (int i = tid; i < NB; i += 256) {
      int c = lcntB[i], g = lstB[i];
      for (int j = 0; j < c; ++j) {
        unsigned int w = words[g + j];
        int r = w >> 24;
        int pos = atomicAdd(&rrun[r], 1);
        adj[p0 + rofs[r] + pos] = (int)(w & 0xFFFFFFu);
      }
    }
  }
}

// ---------------- SpMM gather: 8 lanes/edge, fp32 pooled out --------------
#define ACCUM(V_)                                          \
  acc0 += bf2f((unsigned short)((V_).x & 0xFFFF));         \
  acc1 += bf2f((unsigned short)((V_).x >> 16));            \
  acc2 += bf2f((unsigned short)((V_).y & 0xFFFF));         \
  acc3 += bf2f((unsigned short)((V_).y >> 16));            \
  acc4 += bf2f((unsigned short)((V_).z & 0xFFFF));         \
  acc5 += bf2f((unsigned short)((V_).z >> 16));            \
  acc6 += bf2f((unsigned short)((V_).w & 0xFFFF));         \
  acc7 += bf2f((unsigned short)((V_).w >> 16));
#define RED(a)            \
  a += __shfl_xor(a, 8);  \
  a += __shfl_xor(a, 16); \
  a += __shfl_xor(a, 32);

__global__ __launch_bounds__(256) void k_gather(
    const int* __restrict__ rowptr, const int* __restrict__ adj,
    const unsigned short* __restrict__ hb, const float* __restrict__ invdeg,
    float* __restrict__ pooled, int N) {
  int s = blockIdx.x * 4 + (threadIdx.x >> 6);
  if (s >= N) return;
  const int lane = threadIdx.x & 63;
  const int slot = lane >> 3;  // edge slot 0..7
  const int dp = lane & 7;     // dims 8*dp .. 8*dp+7
  const int e0 = rowptr[s], e1 = rowptr[s + 1];
  float acc0 = 0, acc1 = 0, acc2 = 0, acc3 = 0;
  float acc4 = 0, acc5 = 0, acc6 = 0, acc7 = 0;
  int e = e0 + slot;
  for (; e + 8 < e1; e += 16) {
    int t0 = adj[e], t1 = adj[e + 8];
    uint4 w0 = *(const uint4*)&hb[(size_t)t0 * D + dp * 8];
    uint4 w1 = *(const uint4*)&hb[(size_t)t1 * D + dp * 8];
    ACCUM(w0)
    ACCUM(w1)
  }
  if (e < e1) {
    int t0 = adj[e];
    uint4 w0 = *(const uint4*)&hb[(size_t)t0 * D + dp * 8];
    ACCUM(w0)
  }
  RED(acc0) RED(acc1) RED(acc2) RED(acc3)
  RED(acc4) RED(acc5) RED(acc6) RED(acc7)
  if (slot == 0) {
    float iv = invdeg[s];
    float4 o0 = {acc0 * iv, acc1 * iv, acc2 * iv, acc3 * iv};
    float4 o1 = {acc4 * iv, acc5 * iv, acc6 * iv, acc7 * iv};
    *(float4*)&pooled[(size_t)s * D + dp * 8] = o0;
    *(float4*)&pooled[(size_t)s * D + dp * 8 + 4] = o1;
  }
}

// ---------------- input projection: 32-wide kc chunks, 17.4KB LDS --------
__global__ __launch_bounds__(256) void k_input(
    const float* __restrict__ nf, const float* __restrict__ w,
    const float* __restrict__ bias, const float* __restrict__ bpick,
    const int* __restrict__ picked, float* __restrict__ x,
    unsigned short* __restrict__ hb, int N) {
  __shared__ float aS[64 * 36];
  __shared__ float bs[32 * 64];
  const int tid = threadIdx.x;
  const int r0 = blockIdx.x * 64;
  const int tcol = tid & 15, trow = tid >> 4;
  float4 acc[4];
  float4 bias4 = *(const float4*)&bias[tcol * 4];
#pragma unroll
  for (int r = 0; r < 4; ++r) acc[r] = bias4;

  for (int kc = 0; kc < F; kc += 32) {
    if (kc) __syncthreads();
    for (int i = tid; i < 512; i += 256) {
      int row = i >> 3, k4 = (i & 7) * 4;
      int gr = r0 + row;
      float4 v = (gr < N) ? *(const float4*)&nf[(size_t)gr * F + kc + k4]
                          : make_float4(0.f, 0.f, 0.f, 0.f);
      *(float4*)&aS[row * 36 + k4] = v;
    }
    for (int i = tid; i < 512; i += 256)
      *(float4*)&bs[i * 4] = *(const float4*)&w[kc * 64 + i * 4];
    __syncthreads();
#pragma unroll 4
    for (int k = 0; k < 32; k += 4) {
      float4 b0 = *(const float4*)&bs[(k + 0) * 64 + tcol * 4];
      float4 b1 = *(const float4*)&bs[(k + 1) * 64 + tcol * 4];
      float4 b2 = *(const float4*)&bs[(k + 2) * 64 + tcol * 4];
      float4 b3 = *(const float4*)&bs[(k + 3) * 64 + tcol * 4];
#pragma unroll
      for (int r = 0; r < 4; ++r) {
        float4 a = *(const float4*)&aS[(trow * 4 + r) * 36 + k];
        FMA4(acc[r], a.x, b0)
        FMA4(acc[r], a.y, b1)
        FMA4(acc[r], a.z, b2)
        FMA4(acc[r], a.w, b3)
      }
    }
  }
  int p = *picked;
#pragma unroll
  for (int r = 0; r < 4; ++r) {
    int row = r0 + trow * 4 + r;
    if (row >= N) continue;
    float4 o = acc[r];
    if (row == p) {
      float4 bp = *(const float4*)&bpick[tcol * 4];
      o.x += bp.x;
      o.y += bp.y;
      o.z += bp.z;
      o.w += bp.w;
    }
    *(float4*)&x[(size_t)row * D + tcol * 4] = o;
    ushort4 hv = {f2bf(fmaxf(o.x, 0.f)), f2bf(fmaxf(o.y, 0.f)),
                  f2bf(fmaxf(o.z, 0.f)), f2bf(fmaxf(o.w, 0.f))};
    *(ushort4*)&hb[(size_t)row * D + tcol * 4] = hv;
  }
}

// ---------------- conv round (fp32 pooled, unroll capped) ----------------
__global__ __launch_bounds__(256) void k_conv(
    const float* __restrict__ pooled, const float* __restrict__ x,
    const float* __restrict__ cw, const float* __restrict__ cb,
    float* __restrict__ h, unsigned short* __restrict__ hb,
    float* __restrict__ gsum, int mode, int N) {
  __shared__ float aS[64 * 68];
  __shared__ float bs[64 * 64];
  __shared__ float gs[64];
  const int tid = threadIdx.x;
  const int r0 = blockIdx.x * 64;
  const int tcol = tid & 15, trow = tid >> 4;
  for (int i = tid; i < 1024; i += 256) {
    int row = i >> 4, k4 = (i & 15) * 4;
    int gr = r0 + row;
    float4 v = (gr < N) ? *(const float4*)&pooled[(size_t)gr * D + k4]
                        : make_float4(0.f, 0.f, 0.f, 0.f);
    *(float4*)&aS[row * 68 + k4] = v;
  }
  for (int i = tid; i < 1024; i += 256)
    *(float4*)&bs[i * 4] = *(const float4*)&cw[i * 4];
  __syncthreads();
  float4 acc[4];
  float4 cb4 = *(const float4*)&cb[tcol * 4];
#pragma unroll
  for (int r = 0; r < 4; ++r) acc[r] = cb4;
#pragma unroll 4
  for (int k = 0; k < 64; k += 4) {
    float4 b0 = *(const float4*)&bs[(k + 0) * 64 + tcol * 4];
    float4 b1 = *(const float4*)&bs[(k + 1) * 64 + tcol * 4];
    float4 b2 = *(const float4*)&bs[(k + 2) * 64 + tcol * 4];
    float4 b3 = *(const float4*)&bs[(k + 3) * 64 + tcol * 4];
#pragma unroll
    for (int r = 0; r < 4; ++r) {
      float4 a = *(const float4*)&aS[(trow * 4 + r) * 68 + k];
      FMA4(acc[r], a.x, b0)
      FMA4(acc[r], a.y, b1)
      FMA4(acc[r], a.z, b2)
      FMA4(acc[r], a.w, b3)
    }
  }
  float4 colsum = {0.f, 0.f, 0.f, 0.f};
#pragma unroll
  for (int r = 0; r < 4; ++r) {
    int row = r0 + trow * 4 + r;
    if (row >= N) continue;
    float4 xm = *(const float4*)&x[(size_t)row * D + tcol * 4];
    float h0 = fmaxf(acc[r].x + xm.x, 0.f), h1 = fmaxf(acc[r].y + xm.y, 0.f);
    float h2 = fmaxf(acc[r].z + xm.z, 0.f), h3 = fmaxf(acc[r].w + xm.w, 0.f);
    if (mode == 0) {
      ushort4 hv = {f2bf(h0), f2bf(h1), f2bf(h2), f2bf(h3)};
      *(ushort4*)&hb[(size_t)row * D + tcol * 4] = hv;
    } else {
      *(float4*)&h[(size_t)row * D + tcol * 4] = make_float4(h0, h1, h2, h3);
      colsum.x += h0;
      colsum.y += h1;
      colsum.z += h2;
      colsum.w += h3;
    }
  }
  if (mode == 1) {
    __syncthreads();
    if (tid < 64) gs[tid] = 0.0f;
    __syncthreads();
    atomicAdd(&gs[tcol * 4 + 0], colsum.x);
    atomicAdd(&gs[tcol * 4 + 1], colsum.y);
    atomicAdd(&gs[tcol * 4 + 2], colsum.z);
    atomicAdd(&gs[tcol * 4 + 3], colsum.w);
    __syncthreads();
    if (tid < 64) atomicAdd(&gsum[tid], gs[tid]);
  }
}

// ---------------- final: fused small + GEMM + bilinear --------------------
__global__ __launch_bounds__(256) void k_final(
    const float* __restrict__ h, const float* __restrict__ lin1_w,
    const float* __restrict__ lin1_b, const float* __restrict__ out_w,
    const float* __restrict__ out_b, const int* __restrict__ tgt,
    const float* __restrict__ gsum, float* __restrict__ q, int N) {
  __shared__ float aS[64 * 68];
  __shared__ float bs[64 * 64];
  __shared__ float te[64];
  __shared__ float gbt[64];
  __shared__ float vv[64];
  __shared__ float cc[1];
  const int tid = threadIdx.x;
  const int r0 = blockIdx.x * 64;
  const int tcol = tid & 15, trow = tid >> 4;
  if (tid < 64) te[tid] = h[(size_t)(*tgt) * D + tid];
  for (int i = tid; i < 1024; i += 256) {
    int row = i >> 4, k4 = (i & 15) * 4;
    int gr = r0 + row;
    float4 v = (gr < N) ? *(const float4*)&h[(size_t)gr * D + k4]
                        : make_float4(0.f, 0.f, 0.f, 0.f);
    *(float4*)&aS[row * 68 + k4] = v;
  }
  for (int i = tid; i < 1024; i += 256)
    *(float4*)&bs[i * 4] = *(const float4*)&lin1_w[i * 4];
  __syncthreads();
  if (tid < 64) {
    float invN = 1.0f / (float)N;
    float acc = lin1_b[tid];
    for (int k = 0; k < 64; ++k)
      acc += (gsum[k] * invN) * lin1_w[(64 + k) * 64 + tid];
    gbt[tid] = acc;
  } else if (tid < 128) {
    int j = tid - 64;
    float s = 0.0f;
    for (int d = 0; d < 64; ++d) s += out_w[j * 64 + d] * te[d];
    vv[j] = s;
  } else if (tid == 128) {
    float s = 0.0f;
    for (int d = 0; d < 64; ++d) s += out_b[d] * te[d];
    cc[0] = s;
  }
  __syncthreads();
  float4 acc[4];
  float4 g4 = make_float4(gbt[tcol * 4], gbt[tcol * 4 + 1], gbt[tcol * 4 + 2],
                          gbt[tcol * 4 + 3]);
#pragma unroll
  for (int r = 0; r < 4; ++r) acc[r] = g4;
#pragma unroll 4
  for (int k = 0; k < 64; k += 4) {
    float4 b0 = *(const float4*)&bs[(k + 0) * 64 + tcol * 4];
    float4 b1 = *(const float4*)&bs[(k + 1) * 64 + tcol * 4];
    float4 b2 = *(const float4*)&bs[(k + 2) * 64 + tcol * 4];
    float4 b3 = *(const float4*)&bs[(k + 3) * 64 + tcol * 4];
#pragma unroll
    for (int r = 0; r < 4; ++r) {
      float4 a = *(const float4*)&aS[(trow * 4 + r) * 68 + k];
      FMA4(acc[r], a.x, b0)
      FMA4(acc[r], a.y, b1)
      FMA4(acc[r], a.z, b2)
      FMA4(acc[r], a.w, b3)
    }
  }
  float4 v = make_float4(vv[tcol * 4], vv[tcol * 4 + 1], vv[tcol * 4 + 2],
                         vv[tcol * 4 + 3]);
  float c = cc[0];
#pragma unroll
  for (int r = 0; r < 4; ++r) {
    float p = fmaxf(acc[r].x, 0.f) * v.x + fmaxf(acc[r].y, 0.f) * v.y +
              fmaxf(acc[r].z, 0.f) * v.z + fmaxf(acc[r].w, 0.f) * v.w;
    p += __shfl_xor(p, 1);
    p += __shfl_xor(p, 2);
    p += __shfl_xor(p, 4);
    p += __shfl_xor(p, 8);
    int row = r0 + trow * 4 + r;
    if (tcol == 0 && row < N) q[row] = p + c;
  }
}

extern "C" void kernel_launch(void* const* d_in, const int* in_sizes, int n_in,
                              void* d_out, int out_size, void* d_ws,
                              size_t ws_size, hipStream_t stream) {
  const float* nf = (const float*)d_in[0];
  const float* w_n2l = (const float*)d_in[1];
  const float* b_n2l = (const float*)d_in[2];
  const float* bpick = (const float*)d_in[3];
  const float* conv_w = (const float*)d_in[4];
  const float* conv_b = (const float*)d_in[5];
  const float* lin1_w = (const float*)d_in[6];
  const float* lin1_b = (const float*)d_in[7];
  const float* out_w = (const float*)d_in[8];
  const float* out_b = (const float*)d_in[9];
  const int* esrc = (const int*)d_in[10];
  const int* edst = (const int*)d_in[11];
  const int* tgt = (const int*)d_in[12];
  const int* picked = (const int*)d_in[13];
  float* q = (float*)d_out;

  const int N = in_sizes[0] / F;
  const int E = in_sizes[10];
  const int NBUCK = (N + 255) / 256;   // 782
  const int NB = (E + CH2 - 1) / CH2;  // 782 (<=1024 required)

  char* ws = (char*)d_ws;
  size_t off = 0;
  auto alloc = [&](size_t bytes) {
    void* p = ws + off;
    off = (off + bytes + 255) & ~(size_t)255;
    return p;
  };
  size_t nd = (size_t)N * D * sizeof(float);
  float* x = (float*)alloc(nd);
  float* h = (float*)alloc(nd);
  unsigned short* hb = (unsigned short*)alloc((size_t)N * D * 2);
  float* pooled = (float*)alloc(nd);
  float* invdeg = (float*)alloc((size_t)N * 4);
  int* rowptr = (int*)alloc((size_t)(N + 1) * 4);
  int* adj = (int*)alloc((size_t)E * 4);
  int* ofsmat = (int*)alloc((size_t)NB * 1024 * 4);
  int* ofsmatT = (int*)alloc((size_t)NB * 1024 * 4);
  int* cbh = (int*)alloc(4096 + 8);
  int* cbase = (int*)alloc(4096 + 8);
  float* small = (float*)alloc(1024);
  unsigned int* words = (unsigned int*)x;  // alias: x written after k_part2g

  (void)hipMemsetAsync(cbh, 0, 4096, stream);

  // CSR build: coalesced-write partition -> scan/transpose -> finalize
  k_part1s<<<NB, 256, 0, stream>>>(esrc, edst, cbh, ofsmat, words, E);
  k_cscan<<<1, 1024, 0, stream>>>(cbh, cbase, rowptr, small, N, E);
  dim3 tg((NB + 31) / 32, 32);
  k_transp<<<tg, 256, 0, stream>>>(ofsmat, ofsmatT, NB);
  k_part2g<<<NBUCK, 256, 0, stream>>>(words, ofsmatT, cbase, rowptr, invdeg,
                                      adj, NB, N, E);

  int nb = (N + 63) / 64;
  k_input<<<nb, 256, 0, stream>>>(nf, w_n2l, b_n2l, bpick, picked, x, hb, N);

  for (int lv = 0; lv < 2; ++lv) {
    k_gather<<<(N + 3) / 4, 256, 0, stream>>>(rowptr, adj, hb, invdeg, pooled,
                                              N);
    k_conv<<<nb, 256, 0, stream>>>(pooled, x, conv_w, conv_b, h, hb, small,
                                   (lv == 0) ? 0 : 1, N);
  }

  k_final<<<nb, 256, 0, stream>>>(h, lin1_w, lin1_b, out_w, out_b, tgt, small,
                                  q, N);
}

// Round 19
// 602.482 us; speedup vs baseline: 1.0102x; 1.0102x over previous
//
#include <hip/hip_runtime.h>

#define D 64
#define F 128
#define LDSCAP 12288  // staged words per bucket (48KB) — r17 best config
#define CH2 8192      // edges per part1s block

__device__ __forceinline__ unsigned short f2bf(float f) {
  unsigned int u = __float_as_uint(f);
  unsigned int r = (u + 0x7FFFu + ((u >> 16) & 1u)) >> 16;
  return (unsigned short)r;
}
__device__ __forceinline__ float bf2f(unsigned short h) {
  return __uint_as_float(((unsigned int)h) << 16);
}

#define FMA4(A_, S_, B_) \
  A_.x += (S_) * (B_).x; \
  A_.y += (S_) * (B_).y; \
  A_.z += (S_) * (B_).z; \
  A_.w += (S_) * (B_).w;

// ---- partition pass 1: staged bucket sort, int4 ILP ----------------------
__global__ __launch_bounds__(256) void k_part1s(
    const int* __restrict__ src, const int* __restrict__ dst,
    int* __restrict__ cbh, int* __restrict__ ofsmat,
    unsigned int* __restrict__ words, int E) {
  __shared__ int lhist[1024];
  __shared__ int lofs[1024];
  __shared__ int lrun[1024];
  __shared__ int sc[256];
  __shared__ unsigned int lbuf[CH2];
  const int tid = threadIdx.x;
  const int e0 = blockIdx.x * CH2;
  const int e1 = min(E, e0 + CH2);
  const int csize = e1 - e0;
  const int c4 = csize & ~3;
  for (int i = tid; i < 1024; i += 256) {
    lhist[i] = 0;
    lrun[i] = 0;
  }
  __syncthreads();
  for (int i = e0 + tid * 4; i < e0 + c4; i += 1024) {
    int4 s4 = *(const int4*)&src[i];
    atomicAdd(&lhist[s4.x >> 8], 1);
    atomicAdd(&lhist[s4.y >> 8], 1);
    atomicAdd(&lhist[s4.z >> 8], 1);
    atomicAdd(&lhist[s4.w >> 8], 1);
  }
  for (int i = e0 + c4 + tid; i < e1; i += 256) atomicAdd(&lhist[src[i] >> 8], 1);
  __syncthreads();
  const int b4 = tid * 4;
  int a0 = lhist[b4], a1 = lhist[b4 + 1], a2 = lhist[b4 + 2], a3 = lhist[b4 + 3];
  int ts = a0 + a1 + a2 + a3;
  sc[tid] = ts;
  __syncthreads();
  for (int off = 1; off < 256; off <<= 1) {
    int t = (tid >= off) ? sc[tid - off] : 0;
    __syncthreads();
    sc[tid] += t;
    __syncthreads();
  }
  int ex = sc[tid] - ts;
  lofs[b4] = ex;
  lofs[b4 + 1] = ex + a0;
  lofs[b4 + 2] = ex + a0 + a1;
  lofs[b4 + 3] = ex + a0 + a1 + a2;
  __syncthreads();
  for (int j = tid; j < 1024; j += 256) {
    ofsmat[(size_t)blockIdx.x * 1024 + j] = lofs[j];
    int c = lhist[j];
    if (c) atomicAdd(&cbh[j], c);
  }
  for (int i = e0 + tid * 4; i < e0 + c4; i += 1024) {
    int4 s4 = *(const int4*)&src[i];
    int4 d4 = *(const int4*)&dst[i];
    int b, pos;
    b = s4.x >> 8;
    pos = atomicAdd(&lrun[b], 1);
    lbuf[lofs[b] + pos] = ((unsigned int)(s4.x & 255) << 24) | (unsigned int)d4.x;
    b = s4.y >> 8;
    pos = atomicAdd(&lrun[b], 1);
    lbuf[lofs[b] + pos] = ((unsigned int)(s4.y & 255) << 24) | (unsigned int)d4.y;
    b = s4.z >> 8;
    pos = atomicAdd(&lrun[b], 1);
    lbuf[lofs[b] + pos] = ((unsigned int)(s4.z & 255) << 24) | (unsigned int)d4.z;
    b = s4.w >> 8;
    pos = atomicAdd(&lrun[b], 1);
    lbuf[lofs[b] + pos] = ((unsigned int)(s4.w & 255) << 24) | (unsigned int)d4.w;
  }
  for (int i = e0 + c4 + tid; i < e1; i += 256) {
    int s = src[i];
    int b = s >> 8;
    int pos = atomicAdd(&lrun[b], 1);
    lbuf[lofs[b] + pos] = ((unsigned int)(s & 255) << 24) | (unsigned int)dst[i];
  }
  __syncthreads();
  for (int j = tid; j < (c4 >> 2); j += 256)
    ((uint4*)&words[e0])[j] = ((const uint4*)lbuf)[j];
  for (int j = c4 + tid; j < csize; j += 256) words[e0 + j] = lbuf[j];
}

// ---- coarse scan (+ zero the small buffer) ----------
__global__ __launch_bounds__(1024) void k_cscan(const int* __restrict__ cbh,
                                                int* __restrict__ cbase,
                                                int* __restrict__ rowptr,
                                                float* __restrict__ small_,
                                                int N, int E) {
  __shared__ int s[1024];
  int tid = threadIdx.x;
  if (tid < 256) small_[tid] = 0.0f;
  int v = cbh[tid];
  s[tid] = v;
  __syncthreads();
  for (int off = 1; off < 1024; off <<= 1) {
    int t = (tid >= off) ? s[tid - off] : 0;
    __syncthreads();
    s[tid] += t;
    __syncthreads();
  }
  cbase[tid] = s[tid] - v;
  if (tid == 0) rowptr[N] = E;
}

// ---- ofsmat transpose: [NB][1024] -> [1024][NB] --------------------------
__global__ __launch_bounds__(256) void k_transp(const int* __restrict__ ofsmat,
                                                int* __restrict__ ofsmatT,
                                                int NB) {
  __shared__ int t[32][33];
  const int tx = threadIdx.x & 31, ty = threadIdx.x >> 5;
  const int bi = blockIdx.x * 32;
  const int bj = blockIdx.y * 32;
#pragma unroll
  for (int r = 0; r < 32; r += 8) {
    int i = bi + ty + r;
    t[ty + r][tx] = (i < NB) ? ofsmat[(size_t)i * 1024 + bj + tx] : 0;
  }
  __syncthreads();
#pragma unroll
  for (int r = 0; r < 32; r += 8) {
    int j = bj + ty + r;
    int i = bi + tx;
    if (i < NB) ofsmatT[(size_t)j * NB + i] = t[tx][ty + r];
  }
}

// ---- partition pass 2: serial run-walk (r11-proven) -> CSR ---------------
__global__ __launch_bounds__(256) void k_part2g(
    const unsigned int* __restrict__ words, const int* __restrict__ ofsmatT,
    const int* __restrict__ cbase, int* __restrict__ rowptr,
    float* __restrict__ invdeg, int* __restrict__ adj, int NB, int N, int E) {
  __shared__ int lcntB[1024];
  __shared__ int lstB[1024];
  __shared__ int lplace[1024];
  __shared__ int sc[256];
  __shared__ int rcnt[256];
  __shared__ int rofs[256];
  __shared__ int rrun[256];
  __shared__ unsigned int lwords[LDSCAP];
  const int tid = threadIdx.x;
  const int b = blockIdx.x;
  const int p0 = cbase[b];
  const int total = cbase[b + 1] - p0;
  for (int i = tid; i < 1024; i += 256) {
    lcntB[i] = 0;
    lstB[i] = 0;
  }
  __syncthreads();
  for (int i = tid; i < NB; i += 256) {
    int st = ofsmatT[(size_t)b * NB + i];
    int chunk = min(E - i * CH2, CH2);
    int en = (b == 1023) ? chunk : ofsmatT[(size_t)(b + 1) * NB + i];
    lcntB[i] = en - st;
    lstB[i] = i * CH2 + st;
  }
  __syncthreads();
  const int b4 = tid * 4;
  int a0 = lcntB[b4], a1 = lcntB[b4 + 1], a2 = lcntB[b4 + 2], a3 = lcntB[b4 + 3];
  int ts = a0 + a1 + a2 + a3;
  sc[tid] = ts;
  __syncthreads();
  for (int off = 1; off < 256; off <<= 1) {
    int t = (tid >= off) ? sc[tid - off] : 0;
    __syncthreads();
    sc[tid] += t;
    __syncthreads();
  }
  int ex = sc[tid] - ts;
  lplace[b4] = ex;
  lplace[b4 + 1] = ex + a0;
  lplace[b4 + 2] = ex + a0 + a1;
  lplace[b4 + 3] = ex + a0 + a1 + a2;
  __syncthreads();
  rcnt[tid] = 0;
  rrun[tid] = 0;
  const bool staged = (total <= LDSCAP);
  if (staged) {
    for (int i = tid; i < NB; i += 256) {
      int c = lcntB[i], g = lstB[i], d = lplace[i];
      for (int j = 0; j < c; ++j) lwords[d + j] = words[g + j];
    }
    __syncthreads();
    for (int j = tid; j < total; j += 256) atomicAdd(&rcnt[lwords[j] >> 24], 1);
  } else {
    __syncthreads();
    for (int i = tid; i < NB; i += 256) {
      int c = lcntB[i], g = lstB[i];
      for (int j = 0; j < c; ++j) atomicAdd(&rcnt[words[g + j] >> 24], 1);
    }
  }
  __syncthreads();
  int v = rcnt[tid];
  sc[tid] = v;
  __syncthreads();
  for (int off = 1; off < 256; off <<= 1) {
    int t = (tid >= off) ? sc[tid - off] : 0;
    __syncthreads();
    sc[tid] += t;
    __syncthreads();
  }
  int exr = sc[tid] - v;
  int row = b * 256 + tid;
  if (row < N) {
    rowptr[row] = p0 + exr;
    invdeg[row] = 1.0f / fmaxf((float)v, 1.0f);
  }
  rofs[tid] = exr;
  __syncthreads();
  if (staged) {
    for (int j = tid; j < total; j += 256) {
      unsigned int w = lwords[j];
      int r = w >> 24;
      int pos = atomicAdd(&rrun[r], 1);
      adj[p0 + rofs[r] + pos] = (int)(w & 0xFFFFFFu);
    }
  } else {
    for (int i = tid; i < NB; i += 256) {
      int c = lcntB[i], g = lstB[i];
      for (int j = 0; j < c; ++j) {
        unsigned int w = words[g + j];
        int r = w >> 24;
        int pos = atomicAdd(&rrun[r], 1);
        adj[p0 + rofs[r] + pos] = (int)(w & 0xFFFFFFu);
      }
    }
  }
}

// ---------------- SpMM gather: 8 lanes/edge, fp32 pooled out --------------
#define ACCUM(V_)                                          \
  acc0 += bf2f((unsigned short)((V_).x & 0xFFFF));         \
  acc1 += bf2f((unsigned short)((V_).x >> 16));            \
  acc2 += bf2f((unsigned short)((V_).y & 0xFFFF));         \
  acc3 += bf2f((unsigned short)((V_).y >> 16));            \
  acc4 += bf2f((unsigned short)((V_).z & 0xFFFF));         \
  acc5 += bf2f((unsigned short)((V_).z >> 16));            \
  acc6 += bf2f((unsigned short)((V_).w & 0xFFFF));         \
  acc7 += bf2f((unsigned short)((V_).w >> 16));
#define RED(a)            \
  a += __shfl_xor(a, 8);  \
  a += __shfl_xor(a, 16); \
  a += __shfl_xor(a, 32);

__global__ __launch_bounds__(256) void k_gather(
    const int* __restrict__ rowptr, const int* __restrict__ adj,
    const unsigned short* __restrict__ hb, const float* __restrict__ invdeg,
    float* __restrict__ pooled, int N) {
  int s = blockIdx.x * 4 + (threadIdx.x >> 6);
  if (s >= N) return;
  const int lane = threadIdx.x & 63;
  const int slot = lane >> 3;  // edge slot 0..7
  const int dp = lane & 7;     // dims 8*dp .. 8*dp+7
  const int e0 = rowptr[s], e1 = rowptr[s + 1];
  float acc0 = 0, acc1 = 0, acc2 = 0, acc3 = 0;
  float acc4 = 0, acc5 = 0, acc6 = 0, acc7 = 0;
  int e = e0 + slot;
  for (; e + 8 < e1; e += 16) {
    int t0 = adj[e], t1 = adj[e + 8];
    uint4 w0 = *(const uint4*)&hb[(size_t)t0 * D + dp * 8];
    uint4 w1 = *(const uint4*)&hb[(size_t)t1 * D + dp * 8];
    ACCUM(w0)
    ACCUM(w1)
  }
  if (e < e1) {
    int t0 = adj[e];
    uint4 w0 = *(const uint4*)&hb[(size_t)t0 * D + dp * 8];
    ACCUM(w0)
  }
  RED(acc0) RED(acc1) RED(acc2) RED(acc3)
  RED(acc4) RED(acc5) RED(acc6) RED(acc7)
  if (slot == 0) {
    float iv = invdeg[s];
    float4 o0 = {acc0 * iv, acc1 * iv, acc2 * iv, acc3 * iv};
    float4 o1 = {acc4 * iv, acc5 * iv, acc6 * iv, acc7 * iv};
    *(float4*)&pooled[(size_t)s * D + dp * 8] = o0;
    *(float4*)&pooled[(size_t)s * D + dp * 8 + 4] = o1;
  }
}

// ---------------- input projection: 32-wide kc chunks, 17.4KB LDS --------
__global__ __launch_bounds__(256) void k_input(
    const float* __restrict__ nf, const float* __restrict__ w,
    const float* __restrict__ bias, const float* __restrict__ bpick,
    const int* __restrict__ picked, float* __restrict__ x,
    unsigned short* __restrict__ hb, int N) {
  __shared__ float aS[64 * 36];
  __shared__ float bs[32 * 64];
  const int tid = threadIdx.x;
  const int r0 = blockIdx.x * 64;
  const int tcol = tid & 15, trow = tid >> 4;
  float4 acc[4];
  float4 bias4 = *(const float4*)&bias[tcol * 4];
#pragma unroll
  for (int r = 0; r < 4; ++r) acc[r] = bias4;

  for (int kc = 0; kc < F; kc += 32) {
    if (kc) __syncthreads();
    for (int i = tid; i < 512; i += 256) {
      int row = i >> 3, k4 = (i & 7) * 4;
      int gr = r0 + row;
      float4 v = (gr < N) ? *(const float4*)&nf[(size_t)gr * F + kc + k4]
                          : make_float4(0.f, 0.f, 0.f, 0.f);
      *(float4*)&aS[row * 36 + k4] = v;
    }
    for (int i = tid; i < 512; i += 256)
      *(float4*)&bs[i * 4] = *(const float4*)&w[kc * 64 + i * 4];
    __syncthreads();
#pragma unroll 4
    for (int k = 0; k < 32; k += 4) {
      float4 b0 = *(const float4*)&bs[(k + 0) * 64 + tcol * 4];
      float4 b1 = *(const float4*)&bs[(k + 1) * 64 + tcol * 4];
      float4 b2 = *(const float4*)&bs[(k + 2) * 64 + tcol * 4];
      float4 b3 = *(const float4*)&bs[(k + 3) * 64 + tcol * 4];
#pragma unroll
      for (int r = 0; r < 4; ++r) {
        float4 a = *(const float4*)&aS[(trow * 4 + r) * 36 + k];
        FMA4(acc[r], a.x, b0)
        FMA4(acc[r], a.y, b1)
        FMA4(acc[r], a.z, b2)
        FMA4(acc[r], a.w, b3)
      }
    }
  }
  int p = *picked;
#pragma unroll
  for (int r = 0; r < 4; ++r) {
    int row = r0 + trow * 4 + r;
    if (row >= N) continue;
    float4 o = acc[r];
    if (row == p) {
      float4 bp = *(const float4*)&bpick[tcol * 4];
      o.x += bp.x;
      o.y += bp.y;
      o.z += bp.z;
      o.w += bp.w;
    }
    *(float4*)&x[(size_t)row * D + tcol * 4] = o;
    ushort4 hv = {f2bf(fmaxf(o.x, 0.f)), f2bf(fmaxf(o.y, 0.f)),
                  f2bf(fmaxf(o.z, 0.f)), f2bf(fmaxf(o.w, 0.f))};
    *(ushort4*)&hb[(size_t)row * D + tcol * 4] = hv;
  }
}

// ---------------- conv round (fp32 pooled, unroll capped) ----------------
__global__ __launch_bounds__(256) void k_conv(
    const float* __restrict__ pooled, const float* __restrict__ x,
    const float* __restrict__ cw, const float* __restrict__ cb,
    float* __restrict__ h, unsigned short* __restrict__ hb,
    float* __restrict__ gsum, int mode, int N) {
  __shared__ float aS[64 * 68];
  __shared__ float bs[64 * 64];
  __shared__ float gs[64];
  const int tid = threadIdx.x;
  const int r0 = blockIdx.x * 64;
  const int tcol = tid & 15, trow = tid >> 4;
  for (int i = tid; i < 1024; i += 256) {
    int row = i >> 4, k4 = (i & 15) * 4;
    int gr = r0 + row;
    float4 v = (gr < N) ? *(const float4*)&pooled[(size_t)gr * D + k4]
                        : make_float4(0.f, 0.f, 0.f, 0.f);
    *(float4*)&aS[row * 68 + k4] = v;
  }
  for (int i = tid; i < 1024; i += 256)
    *(float4*)&bs[i * 4] = *(const float4*)&cw[i * 4];
  __syncthreads();
  float4 acc[4];
  float4 cb4 = *(const float4*)&cb[tcol * 4];
#pragma unroll
  for (int r = 0; r < 4; ++r) acc[r] = cb4;
#pragma unroll 4
  for (int k = 0; k < 64; k += 4) {
    float4 b0 = *(const float4*)&bs[(k + 0) * 64 + tcol * 4];
    float4 b1 = *(const float4*)&bs[(k + 1) * 64 + tcol * 4];
    float4 b2 = *(const float4*)&bs[(k + 2) * 64 + tcol * 4];
    float4 b3 = *(const float4*)&bs[(k + 3) * 64 + tcol * 4];
#pragma unroll
    for (int r = 0; r < 4; ++r) {
      float4 a = *(const float4*)&aS[(trow * 4 + r) * 68 + k];
      FMA4(acc[r], a.x, b0)
      FMA4(acc[r], a.y, b1)
      FMA4(acc[r], a.z, b2)
      FMA4(acc[r], a.w, b3)
    }
  }
  float4 colsum = {0.f, 0.f, 0.f, 0.f};
#pragma unroll
  for (int r = 0; r < 4; ++r) {
    int row = r0 + trow * 4 + r;
    if (row >= N) continue;
    float4 xm = *(const float4*)&x[(size_t)row * D + tcol * 4];
    float h0 = fmaxf(acc[r].x + xm.x, 0.f), h1 = fmaxf(acc[r].y + xm.y, 0.f);
    float h2 = fmaxf(acc[r].z + xm.z, 0.f), h3 = fmaxf(acc[r].w + xm.w, 0.f);
    if (mode == 0) {
      ushort4 hv = {f2bf(h0), f2bf(h1), f2bf(h2), f2bf(h3)};
      *(ushort4*)&hb[(size_t)row * D + tcol * 4] = hv;
    } else {
      *(float4*)&h[(size_t)row * D + tcol * 4] = make_float4(h0, h1, h2, h3);
      colsum.x += h0;
      colsum.y += h1;
      colsum.z += h2;
      colsum.w += h3;
    }
  }
  if (mode == 1) {
    __syncthreads();
    if (tid < 64) gs[tid] = 0.0f;
    __syncthreads();
    atomicAdd(&gs[tcol * 4 + 0], colsum.x);
    atomicAdd(&gs[tcol * 4 + 1], colsum.y);
    atomicAdd(&gs[tcol * 4 + 2], colsum.z);
    atomicAdd(&gs[tcol * 4 + 3], colsum.w);
    __syncthreads();
    if (tid < 64) atomicAdd(&gsum[tid], gs[tid]);
  }
}

// ---------------- final: fused small + GEMM + bilinear --------------------
__global__ __launch_bounds__(256) void k_final(
    const float* __restrict__ h, const float* __restrict__ lin1_w,
    const float* __restrict__ lin1_b, const float* __restrict__ out_w,
    const float* __restrict__ out_b, const int* __restrict__ tgt,
    const float* __restrict__ gsum, float* __restrict__ q, int N) {
  __shared__ float aS[64 * 68];
  __shared__ float bs[64 * 64];
  __shared__ float te[64];
  __shared__ float gbt[64];
  __shared__ float vv[64];
  __shared__ float cc[1];
  const int tid = threadIdx.x;
  const int r0 = blockIdx.x * 64;
  const int tcol = tid & 15, trow = tid >> 4;
  if (tid < 64) te[tid] = h[(size_t)(*tgt) * D + tid];
  for (int i = tid; i < 1024; i += 256) {
    int row = i >> 4, k4 = (i & 15) * 4;
    int gr = r0 + row;
    float4 v = (gr < N) ? *(const float4*)&h[(size_t)gr * D + k4]
                        : make_float4(0.f, 0.f, 0.f, 0.f);
    *(float4*)&aS[row * 68 + k4] = v;
  }
  for (int i = tid; i < 1024; i += 256)
    *(float4*)&bs[i * 4] = *(const float4*)&lin1_w[i * 4];
  __syncthreads();
  if (tid < 64) {
    float invN = 1.0f / (float)N;
    float acc = lin1_b[tid];
    for (int k = 0; k < 64; ++k)
      acc += (gsum[k] * invN) * lin1_w[(64 + k) * 64 + tid];
    gbt[tid] = acc;
  } else if (tid < 128) {
    int j = tid - 64;
    float s = 0.0f;
    for (int d = 0; d < 64; ++d) s += out_w[j * 64 + d] * te[d];
    vv[j] = s;
  } else if (tid == 128) {
    float s = 0.0f;
    for (int d = 0; d < 64; ++d) s += out_b[d] * te[d];
    cc[0] = s;
  }
  __syncthreads();
  float4 acc[4];
  float4 g4 = make_float4(gbt[tcol * 4], gbt[tcol * 4 + 1], gbt[tcol * 4 + 2],
                          gbt[tcol * 4 + 3]);
#pragma unroll
  for (int r = 0; r < 4; ++r) acc[r] = g4;
#pragma unroll 4
  for (int k = 0; k < 64; k += 4) {
    float4 b0 = *(const float4*)&bs[(k + 0) * 64 + tcol * 4];
    float4 b1 = *(const float4*)&bs[(k + 1) * 64 + tcol * 4];
    float4 b2 = *(const float4*)&bs[(k + 2) * 64 + tcol * 4];
    float4 b3 = *(const float4*)&bs[(k + 3) * 64 + tcol * 4];
#pragma unroll
    for (int r = 0; r < 4; ++r) {
      float4 a = *(const float4*)&aS[(trow * 4 + r) * 68 + k];
      FMA4(acc[r], a.x, b0)
      FMA4(acc[r], a.y, b1)
      FMA4(acc[r], a.z, b2)
      FMA4(acc[r], a.w, b3)
    }
  }
  float4 v = make_float4(vv[tcol * 4], vv[tcol * 4 + 1], vv[tcol * 4 + 2],
                         vv[tcol * 4 + 3]);
  float c = cc[0];
#pragma unroll
  for (int r = 0; r < 4; ++r) {
    float p = fmaxf(acc[r].x, 0.f) * v.x + fmaxf(acc[r].y, 0.f) * v.y +
              fmaxf(acc[r].z, 0.f) * v.z + fmaxf(acc[r].w, 0.f) * v.w;
    p += __shfl_xor(p, 1);
    p += __shfl_xor(p, 2);
    p += __shfl_xor(p, 4);
    p += __shfl_xor(p, 8);
    int row = r0 + trow * 4 + r;
    if (tcol == 0 && row < N) q[row] = p + c;
  }
}

extern "C" void kernel_launch(void* const* d_in, const int* in_sizes, int n_in,
                              void* d_out, int out_size, void* d_ws,
                              size_t ws_size, hipStream_t stream) {
  const float* nf = (const float*)d_in[0];
  const float* w_n2l = (const float*)d_in[1];
  const float* b_n2l = (const float*)d_in[2];
  const float* bpick = (const float*)d_in[3];
  const float* conv_w = (const float*)d_in[4];
  const float* conv_b = (const float*)d_in[5];
  const float* lin1_w = (const float*)d_in[6];
  const float* lin1_b = (const float*)d_in[7];
  const float* out_w = (const float*)d_in[8];
  const float* out_b = (const float*)d_in[9];
  const int* esrc = (const int*)d_in[10];
  const int* edst = (const int*)d_in[11];
  const int* tgt = (const int*)d_in[12];
  const int* picked = (const int*)d_in[13];
  float* q = (float*)d_out;

  const int N = in_sizes[0] / F;
  const int E = in_sizes[10];
  const int NBUCK = (N + 255) / 256;   // 782
  const int NB = (E + CH2 - 1) / CH2;  // 782 (<=1024 required)

  char* ws = (char*)d_ws;
  size_t off = 0;
  auto alloc = [&](size_t bytes) {
    void* p = ws + off;
    off = (off + bytes + 255) & ~(size_t)255;
    return p;
  };
  size_t nd = (size_t)N * D * sizeof(float);
  float* x = (float*)alloc(nd);
  float* h = (float*)alloc(nd);
  unsigned short* hb = (unsigned short*)alloc((size_t)N * D * 2);
  float* pooled = (float*)alloc(nd);
  float* invdeg = (float*)alloc((size_t)N * 4);
  int* rowptr = (int*)alloc((size_t)(N + 1) * 4);
  int* adj = (int*)alloc((size_t)E * 4);
  int* ofsmat = (int*)alloc((size_t)NB * 1024 * 4);
  int* ofsmatT = (int*)alloc((size_t)NB * 1024 * 4);
  int* cbh = (int*)alloc(4096 + 8);
  int* cbase = (int*)alloc(4096 + 8);
  float* small = (float*)alloc(1024);
  unsigned int* words = (unsigned int*)x;  // alias: x written after k_part2g

  (void)hipMemsetAsync(cbh, 0, 4096, stream);

  // CSR build: coalesced-write partition -> scan/transpose -> finalize
  k_part1s<<<NB, 256, 0, stream>>>(esrc, edst, cbh, ofsmat, words, E);
  k_cscan<<<1, 1024, 0, stream>>>(cbh, cbase, rowptr, small, N, E);
  dim3 tg((NB + 31) / 32, 32);
  k_transp<<<tg, 256, 0, stream>>>(ofsmat, ofsmatT, NB);
  k_part2g<<<NBUCK, 256, 0, stream>>>(words, ofsmatT, cbase, rowptr, invdeg,
                                      adj, NB, N, E);

  int nb = (N + 63) / 64;
  k_input<<<nb, 256, 0, stream>>>(nf, w_n2l, b_n2l, bpick, picked, x, hb, N);

  for (int lv = 0; lv < 2; ++lv) {
    k_gather<<<(N + 3) / 4, 256, 0, stream>>>(rowptr, adj, hb, invdeg, pooled,
                                              N);
    k_conv<<<nb, 256, 0, stream>>>(pooled, x, conv_w, conv_b, h, hb, small,
                                   (lv == 0) ? 0 : 1, N);
  }

  k_final<<<nb, 256, 0, stream>>>(h, lin1_w, lin1_b, out_w, out_b, tgt, small,
                                  q, N);
}